// Round 2
// baseline (5340.396 us; speedup 1.0000x reference)
//
#include <hip/hip_runtime.h>
#include <cstdint>

typedef _Float16 half8 __attribute__((ext_vector_type(8)));
typedef _Float16 half4v __attribute__((ext_vector_type(4)));
typedef float floatx4 __attribute__((ext_vector_type(4)));
typedef unsigned long long u64;

__device__ __forceinline__ float sig_(float x) { return 1.f / (1.f + __expf(-x)); }
__device__ __forceinline__ float tanh_(float x) {
  x = fminf(15.f, fmaxf(-15.f, x));
  float e = __expf(2.f * x);
  return (e - 1.f) / (e + 1.f);
}

// ---------------- prep kernels ----------------
__global__ void cvt_x_kernel(const float* __restrict__ x, _Float16* __restrict__ xh, int n) {
  int i = (blockIdx.x * 256 + threadIdx.x) * 4;
  if (i < n) {
    const float4 v = *(const float4*)(x + i);
    half4v o = {(_Float16)v.x, (_Float16)v.y, (_Float16)v.z, (_Float16)v.w};
    *(half4v*)(xh + i) = o;
  }
}

// Permuted weights: row n of W*perm = w_{g}[u][:], u=n>>2, g=n&3.
// Block p of the recurrent kernel owns contiguous perm-cols [16p,16p+16).
__global__ void build_w_kernel(const float* w0, const float* w1, const float* w2, const float* w3,
                               const float* w4, const float* w5, const float* w6, const float* w7,
                               const float* b0, const float* b1, const float* b2, const float* b3,
                               _Float16* __restrict__ Wip, _Float16* __restrict__ Whp,
                               float* __restrict__ biasp) {
  int n = blockIdx.x;
  if (n < 8192) {
    const float* srcs[8] = {w0, w1, w2, w3, w4, w5, w6, w7};
    int which = n >> 12;
    int row = n & 4095;
    int u = row >> 2, g = row & 3;
    const float* s = srcs[which * 4 + g] + (size_t)u * 1024;
    _Float16* dst = (which ? Whp : Wip) + (size_t)row * 1024;
    int t = threadIdx.x * 4;
    float4 v = *(const float4*)(s + t);
    half4v o = {(_Float16)v.x, (_Float16)v.y, (_Float16)v.z, (_Float16)v.w};
    *(half4v*)(dst + t) = o;
  } else {
    const float* bs[4] = {b0, b1, b2, b3};
    for (int idx = threadIdx.x; idx < 4096; idx += 256)
      biasp[idx] = bs[idx & 3][idx >> 2];
  }
}

// h buffers: fp16 pairs packed in u32, row-major [batch][unit]
__global__ void init_h_kernel(const float* __restrict__ hx, unsigned int* __restrict__ hbuf) {
  int i = blockIdx.x * 256 + threadIdx.x;
  if (i < 32768) {
    unsigned short lo = __builtin_bit_cast(unsigned short, (_Float16)hx[2 * i]);
    unsigned short hi = __builtin_bit_cast(unsigned short, (_Float16)hx[2 * i + 1]);
    hbuf[i] = (unsigned int)lo | ((unsigned int)hi << 16);
  }
}

__global__ void zero_flags_kernel(unsigned int* __restrict__ flags) {
  int i = blockIdx.x * 256 + threadIdx.x;
  if (i < 8192) flags[i] = 0u;
}

// ---------------- precompute GEMM ----------------
// G3 layout (fp16): [p(256)][t(512)][i(4)][kg(4)][ml(16)][r(4)] — matches rec-kernel
// lane layout so the rec kernel reads one coalesced u64 per thread per step.
__global__ __launch_bounds__(256) void gemm_g_kernel(const _Float16* __restrict__ Xh,
                                                     const _Float16* __restrict__ Wp,
                                                     const float* __restrict__ biasp,
                                                     _Float16* __restrict__ G3) {
  __shared__ _Float16 Al[4][128][8];
  __shared__ _Float16 Bl[4][128][8];
  const int tid = threadIdx.x;
  const int w = tid >> 6, l = tid & 63;
  const int wm = (w >> 1) * 64, wn = (w & 1) * 64;
  const int ml = l & 15, kg = l >> 4;
  const int bm = blockIdx.x, bn = blockIdx.y;
  const int r0 = tid & 127, kc0 = tid >> 7;
  const int kc1 = kc0 + 2;
  const size_t arow0 = (size_t)(bm * 128 + r0) * 1024;
  const size_t brow0 = (size_t)(bn * 128 + r0) * 1024;
  floatx4 acc[4][4] = {};
  for (int kt = 0; kt < 1024; kt += 32) {
    __syncthreads();
    __builtin_amdgcn_global_load_lds(
        (const __attribute__((address_space(1))) unsigned int*)(Xh + arow0 + kt + kc0 * 8),
        (__attribute__((address_space(3))) unsigned int*)&Al[kc0][r0][0], 16, 0, 0);
    __builtin_amdgcn_global_load_lds(
        (const __attribute__((address_space(1))) unsigned int*)(Xh + arow0 + kt + kc1 * 8),
        (__attribute__((address_space(3))) unsigned int*)&Al[kc1][r0][0], 16, 0, 0);
    __builtin_amdgcn_global_load_lds(
        (const __attribute__((address_space(1))) unsigned int*)(Wp + brow0 + kt + kc0 * 8),
        (__attribute__((address_space(3))) unsigned int*)&Bl[kc0][r0][0], 16, 0, 0);
    __builtin_amdgcn_global_load_lds(
        (const __attribute__((address_space(1))) unsigned int*)(Wp + brow0 + kt + kc1 * 8),
        (__attribute__((address_space(3))) unsigned int*)&Bl[kc1][r0][0], 16, 0, 0);
    __syncthreads();
    half8 af[4], bf[4];
#pragma unroll
    for (int i = 0; i < 4; ++i) af[i] = *(const half8*)&Al[kg][wm + i * 16 + ml][0];
#pragma unroll
    for (int j = 0; j < 4; ++j) bf[j] = *(const half8*)&Bl[kg][wn + j * 16 + ml][0];
#pragma unroll
    for (int i = 0; i < 4; ++i)
#pragma unroll
      for (int j = 0; j < 4; ++j)
        acc[i][j] = __builtin_amdgcn_mfma_f32_16x16x32_f16(af[i], bf[j], acc[i][j], 0, 0, 0);
  }
  const int t = (bm * 128 + wm) >> 6;  // wm in {0,64} -> t const per wave
#pragma unroll
  for (int j = 0; j < 4; ++j) {
    const int col = bn * 128 + wn + j * 16 + ml;
    const float bj = biasp[col];
    const int p = col >> 4;
#pragma unroll
    for (int i = 0; i < 4; ++i) {
      half4v pk = {(_Float16)(acc[i][j][0] + bj), (_Float16)(acc[i][j][1] + bj),
                   (_Float16)(acc[i][j][2] + bj), (_Float16)(acc[i][j][3] + bj)};
      *(half4v*)&G3[((size_t)p * 512 + t) * 1024 + i * 256 + kg * 64 + ml * 4] = pk;
    }
  }
}

// ---------------- persistent recurrent kernel ----------------
// 256 blocks (1/CU) x 4 waves. Block p owns units [4p,4p+4) = perm cols [16p,16p+16).
// Wh fragments persistent in registers (128 VGPR). Each wave stages its own 16 h-rows
// into its private LDS slice with coalesced agent-atomic u64 loads; XOR-swizzled so
// frag ds_read_b128 is conflict-free. NO __syncthreads anywhere in the loop:
// per-block completion is aggregated with an LDS atomic counter (each wave adds after
// its own vmcnt(0) drain; the 4th wave stores flags[p]); wave 0 polls all 256 flags
// with 2 coalesced u64 loads/lane and releases siblings via an LDS token.
__global__ __launch_bounds__(256, 1) void lstm_rec_kernel(
    const _Float16* __restrict__ G3, const _Float16* __restrict__ Whp,
    unsigned int* __restrict__ hbuf, const float* __restrict__ cx,
    float* __restrict__ out, unsigned int* __restrict__ flags) {
  const int p = blockIdx.x, tid = threadIdx.x;
  const int w = tid >> 6, l = tid & 63;
  const int ml = l & 15, kg = l >> 4;
  __shared__ _Float16 hl_[32768];        // 64 KB; wave w slice = hl_[w*8192 ..]
  __shared__ unsigned ctr, tok;
  char* hl = (char*)(hl_ + w * 8192);    // 16 rows x 512 fp16 (1024 B/row)

  // persistent Wh B-fragments: lane (ml,kg) holds Whp[16p+ml][s*32+kg*8 .. +8]
  half8 wfr[32];
#pragma unroll
  for (int s = 0; s < 32; ++s)
    wfr[s] = *(const half8*)&Whp[(size_t)(16 * p + ml) * 1024 + s * 32 + kg * 8];

  const int bl = l >> 2, u = l & 3;
  const int bglob = 16 * w + bl, U = 4 * p + u;
  float c = cx[bglob * 1024 + U];
  if (tid == 0) { ctr = 0u; tok = 0u; }
  __syncthreads();

  for (int t = 0; t < 512; ++t) {
    const u64* hq = (const u64*)(hbuf + (size_t)(t & 1) * 32768);
    u64* hnq = (u64*)(hbuf + (size_t)((t & 1) ^ 1) * 32768);

    // ---- issue all global traffic up front (coalesced) ----
    u64 c1[32], c2[32];
#pragma unroll
    for (int i = 0; i < 32; ++i) {
      const int row = i >> 1, j = ((i & 1) << 6) + l;
      c1[i] = __hip_atomic_load(&hq[(size_t)(16 * w + row) * 256 + j], __ATOMIC_RELAXED,
                                __HIP_MEMORY_SCOPE_AGENT);
    }
    const u64 ginb =
        *(const u64*)&G3[((size_t)p * 512 + t) * 1024 + w * 256 + kg * 64 + ml * 4];
#pragma unroll
    for (int i = 0; i < 32; ++i) {
      const int row = i >> 1, j = ((i & 1) << 6) + l;
      c2[i] = __hip_atomic_load(&hq[(size_t)(16 * w + row) * 256 + 128 + j], __ATOMIC_RELAXED,
                                __HIP_MEMORY_SCOPE_AGENT);
    }

    // ---- chunk 1: stage + MFMA (same-wave LDS, no block sync) ----
#pragma unroll
    for (int i = 0; i < 32; ++i) {
      const int row = i >> 1, j = ((i & 1) << 6) + l;
      const int un = (j >> 1) ^ (row & 7);
      *(u64*)(hl + row * 1024 + un * 16 + (j & 1) * 8) = c1[i];
    }
    __builtin_amdgcn_wave_barrier();
    floatx4 acc[4] = {};
#pragma unroll
    for (int s = 0; s < 16; ++s) {
      const int un = (s * 4 + kg) ^ (ml & 7);
      half8 a = *(const half8*)(hl + ml * 1024 + un * 16);
      acc[s & 3] = __builtin_amdgcn_mfma_f32_16x16x32_f16(a, wfr[s], acc[s & 3], 0, 0, 0);
    }
    __builtin_amdgcn_wave_barrier();
    // ---- chunk 2 ----
#pragma unroll
    for (int i = 0; i < 32; ++i) {
      const int row = i >> 1, j = ((i & 1) << 6) + l;
      const int un = (j >> 1) ^ (row & 7);
      *(u64*)(hl + row * 1024 + un * 16 + (j & 1) * 8) = c2[i];
    }
    __builtin_amdgcn_wave_barrier();
#pragma unroll
    for (int s = 0; s < 16; ++s) {
      const int un = (s * 4 + kg) ^ (ml & 7);
      half8 a = *(const half8*)(hl + ml * 1024 + un * 16);
      acc[s & 3] = __builtin_amdgcn_mfma_f32_16x16x32_f16(a, wfr[16 + s], acc[s & 3], 0, 0, 0);
    }
    floatx4 a4 = (acc[0] + acc[1]) + (acc[2] + acc[3]);

    // ---- intra-wave gate exchange in own slice (frag reads already issued) ----
    union { u64 q; half4v h4; } gu; gu.q = ginb;
    float* glw = (float*)hl;  // 16x20 f32 = 1280 B, inside own 16 KB slice
    __builtin_amdgcn_wave_barrier();
#pragma unroll
    for (int r = 0; r < 4; ++r)
      glw[(kg * 4 + r) * 20 + ml] = a4[r] + (float)gu.h4[r];
    __builtin_amdgcn_wave_barrier();
    const float4 g4 = *(const float4*)&glw[bl * 20 + u * 4];

    const float ig = sig_(g4.x), fg = sig_(g4.y);
    const float ag = tanh_(g4.z), og = sig_(g4.w);
    c = fg * c + ig * ag;
    const float h = og * tanh_(c);

    // publish: pack 4 units/batch -> one u64 agent store from lane u==0
    unsigned int mine = (unsigned int)__builtin_bit_cast(unsigned short, (_Float16)h);
    unsigned int pair = mine | (((unsigned int)__shfl_xor((int)mine, 1)) << 16);
    u64 quad = (u64)pair | ((u64)(unsigned int)__shfl_xor((int)pair, 2) << 32);
    if (u == 0)
      __hip_atomic_store(&hnq[(size_t)bglob * 256 + p], quad, __ATOMIC_RELAXED,
                         __HIP_MEMORY_SCOPE_AGENT);

    if (t == 511) {
      out[(size_t)t * 65536 + bglob * 1024 + U] = h;
      out[(size_t)33554432 + bglob * 1024 + U] = h;  // hy
      out[(size_t)33619968 + bglob * 1024 + U] = c;  // cy
      break;
    }

    // ---- wave-autonomous grid barrier (no __syncthreads) ----
    __builtin_amdgcn_s_waitcnt(0x0F70);  // vmcnt(0): own publish acked at LLC
    const unsigned tgt = (unsigned)(t + 1);
    if (l == 0) {
      unsigned rank = __hip_atomic_fetch_add(&ctr, 1u, __ATOMIC_RELAXED,
                                             __HIP_MEMORY_SCOPE_WORKGROUP);
      if ((rank & 3u) == 3u)  // 4th wave of this step: all publishes acked
        __hip_atomic_store(&flags[p], tgt, __ATOMIC_RELAXED, __HIP_MEMORY_SCOPE_AGENT);
    }
    out[(size_t)t * 65536 + bglob * 1024 + U] = h;  // off the critical path
    if (w == 0) {
      // coalesced poll: lane l covers flags[4l..4l+3] via two u64 loads (16 lines total)
      const u64* f64 = (const u64*)flags;
      int done;
      do {
        u64 v0 = __hip_atomic_load(&f64[2 * l], __ATOMIC_RELAXED, __HIP_MEMORY_SCOPE_AGENT);
        u64 v1 = __hip_atomic_load(&f64[2 * l + 1], __ATOMIC_RELAXED, __HIP_MEMORY_SCOPE_AGENT);
        done = __all(((unsigned)v0 >= tgt) & ((unsigned)(v0 >> 32) >= tgt) &
                     ((unsigned)v1 >= tgt) & ((unsigned)(v1 >> 32) >= tgt));
      } while (!done);
      __hip_atomic_store(&tok, tgt, __ATOMIC_RELAXED, __HIP_MEMORY_SCOPE_WORKGROUP);
    } else {
      while (__hip_atomic_load(&tok, __ATOMIC_RELAXED, __HIP_MEMORY_SCOPE_WORKGROUP) < tgt) {}
    }
    asm volatile("" ::: "memory");
  }
}

// ---------------- launch ----------------
extern "C" void kernel_launch(void* const* d_in, const int* in_sizes, int n_in,
                              void* d_out, int out_size, void* d_ws, size_t ws_size,
                              hipStream_t stream) {
  const float* x    = (const float*)d_in[0];
  const float* hx   = (const float*)d_in[1];
  const float* cxp  = (const float*)d_in[2];
  const float* w_ii = (const float*)d_in[3];
  const float* w_fi = (const float*)d_in[4];
  const float* w_ai = (const float*)d_in[5];
  const float* w_oi = (const float*)d_in[6];
  const float* w_ih = (const float*)d_in[7];
  const float* w_fh = (const float*)d_in[8];
  const float* w_ah = (const float*)d_in[9];
  const float* w_oh = (const float*)d_in[10];
  const float* b_i  = (const float*)d_in[11];
  const float* b_f  = (const float*)d_in[12];
  const float* b_a  = (const float*)d_in[13];
  const float* b_o  = (const float*)d_in[14];
  float* out = (float*)d_out;

  char* ws = (char*)d_ws;
  _Float16* Xh        = (_Float16*)(ws);                 // 64 MB (dead after gemm_g)
  unsigned int* flags = (unsigned int*)(ws);             // 1 KB used, aliases Xh
  _Float16* Wip       = (_Float16*)(ws + 67108864);      // 8 MB
  _Float16* Whp       = (_Float16*)(ws + 75497472);      // 8 MB
  float* biasp        = (float*)(ws + 83886080);         // 16 KB
  unsigned int* hbuf  = (unsigned int*)(ws + 83902464);  // 256 KB (2 packed buffers)
  _Float16* G3        = (_Float16*)(ws + 84164864);      // 256 MB
  if (ws_size < (size_t)84164864 + 268435456) return;

  cvt_x_kernel<<<32768, 256, 0, stream>>>(x, Xh, 33554432);
  build_w_kernel<<<8193, 256, 0, stream>>>(w_ii, w_fi, w_ai, w_oi, w_ih, w_fh, w_ah, w_oh,
                                           b_i, b_f, b_a, b_o, Wip, Whp, biasp);
  init_h_kernel<<<128, 256, 0, stream>>>(hx, hbuf);
  gemm_g_kernel<<<dim3(256, 32), 256, 0, stream>>>(Xh, Wip, biasp, G3);
  zero_flags_kernel<<<32, 256, 0, stream>>>(flags);
  lstm_rec_kernel<<<256, 256, 0, stream>>>(G3, Whp, hbuf, cxp, out, flags);
}

// Round 3
// 3453.038 us; speedup vs baseline: 1.5466x; 1.5466x over previous
//
#include <hip/hip_runtime.h>
#include <cstdint>

typedef _Float16 half8 __attribute__((ext_vector_type(8)));
typedef _Float16 half4v __attribute__((ext_vector_type(4)));
typedef float floatx4 __attribute__((ext_vector_type(4)));
typedef unsigned long long u64;

__device__ __forceinline__ float sig_(float x) { return 1.f / (1.f + __expf(-x)); }
__device__ __forceinline__ float tanh_(float x) {
  x = fminf(15.f, fmaxf(-15.f, x));
  float e = __expf(2.f * x);
  return (e - 1.f) / (e + 1.f);
}

// ---------------- prep kernels ----------------
__global__ void cvt_x_kernel(const float* __restrict__ x, _Float16* __restrict__ xh, int n) {
  int i = (blockIdx.x * 256 + threadIdx.x) * 4;
  if (i < n) {
    const float4 v = *(const float4*)(x + i);
    half4v o = {(_Float16)v.x, (_Float16)v.y, (_Float16)v.z, (_Float16)v.w};
    *(half4v*)(xh + i) = o;
  }
}

// Permuted weights: row n of W*perm = w_{g}[u][:], u=n>>2, g=n&3.
__global__ void build_w_kernel(const float* w0, const float* w1, const float* w2, const float* w3,
                               const float* w4, const float* w5, const float* w6, const float* w7,
                               const float* b0, const float* b1, const float* b2, const float* b3,
                               _Float16* __restrict__ Wip, _Float16* __restrict__ Whp,
                               float* __restrict__ biasp) {
  int n = blockIdx.x;
  if (n < 8192) {
    const float* srcs[8] = {w0, w1, w2, w3, w4, w5, w6, w7};
    int which = n >> 12;
    int row = n & 4095;
    int u = row >> 2, g = row & 3;
    const float* s = srcs[which * 4 + g] + (size_t)u * 1024;
    _Float16* dst = (which ? Whp : Wip) + (size_t)row * 1024;
    int t = threadIdx.x * 4;
    float4 v = *(const float4*)(s + t);
    half4v o = {(_Float16)v.x, (_Float16)v.y, (_Float16)v.z, (_Float16)v.w};
    *(half4v*)(dst + t) = o;
  } else {
    const float* bs[4] = {b0, b1, b2, b3};
    for (int idx = threadIdx.x; idx < 4096; idx += 256)
      biasp[idx] = bs[idx & 3][idx >> 2];
  }
}

// h buffers: fp16 pairs packed in u32, row-major [batch][unit]
__global__ void init_h_kernel(const float* __restrict__ hx, unsigned int* __restrict__ hbuf) {
  int i = blockIdx.x * 256 + threadIdx.x;
  if (i < 32768) {
    unsigned short lo = __builtin_bit_cast(unsigned short, (_Float16)hx[2 * i]);
    unsigned short hi = __builtin_bit_cast(unsigned short, (_Float16)hx[2 * i + 1]);
    hbuf[i] = (unsigned int)lo | ((unsigned int)hi << 16);
  }
}

__global__ void zero_flags_kernel(unsigned int* __restrict__ flags) {
  int i = blockIdx.x * 256 + threadIdx.x;
  if (i < 8192) flags[i] = 0u;
}

// ---------------- precompute GEMM ----------------
// G3 layout (fp16): [p(256)][t(512)][i(4)][kg(4)][ml(16)][r(4)] — unchanged.
__global__ __launch_bounds__(256) void gemm_g_kernel(const _Float16* __restrict__ Xh,
                                                     const _Float16* __restrict__ Wp,
                                                     const float* __restrict__ biasp,
                                                     _Float16* __restrict__ G3) {
  __shared__ _Float16 Al[4][128][8];
  __shared__ _Float16 Bl[4][128][8];
  const int tid = threadIdx.x;
  const int w = tid >> 6, l = tid & 63;
  const int wm = (w >> 1) * 64, wn = (w & 1) * 64;
  const int ml = l & 15, kg = l >> 4;
  const int bm = blockIdx.x, bn = blockIdx.y;
  const int r0 = tid & 127, kc0 = tid >> 7;
  const int kc1 = kc0 + 2;
  const size_t arow0 = (size_t)(bm * 128 + r0) * 1024;
  const size_t brow0 = (size_t)(bn * 128 + r0) * 1024;
  floatx4 acc[4][4] = {};
  for (int kt = 0; kt < 1024; kt += 32) {
    __syncthreads();
    __builtin_amdgcn_global_load_lds(
        (const __attribute__((address_space(1))) unsigned int*)(Xh + arow0 + kt + kc0 * 8),
        (__attribute__((address_space(3))) unsigned int*)&Al[kc0][r0][0], 16, 0, 0);
    __builtin_amdgcn_global_load_lds(
        (const __attribute__((address_space(1))) unsigned int*)(Xh + arow0 + kt + kc1 * 8),
        (__attribute__((address_space(3))) unsigned int*)&Al[kc1][r0][0], 16, 0, 0);
    __builtin_amdgcn_global_load_lds(
        (const __attribute__((address_space(1))) unsigned int*)(Wp + brow0 + kt + kc0 * 8),
        (__attribute__((address_space(3))) unsigned int*)&Bl[kc0][r0][0], 16, 0, 0);
    __builtin_amdgcn_global_load_lds(
        (const __attribute__((address_space(1))) unsigned int*)(Wp + brow0 + kt + kc1 * 8),
        (__attribute__((address_space(3))) unsigned int*)&Bl[kc1][r0][0], 16, 0, 0);
    __syncthreads();
    half8 af[4], bf[4];
#pragma unroll
    for (int i = 0; i < 4; ++i) af[i] = *(const half8*)&Al[kg][wm + i * 16 + ml][0];
#pragma unroll
    for (int j = 0; j < 4; ++j) bf[j] = *(const half8*)&Bl[kg][wn + j * 16 + ml][0];
#pragma unroll
    for (int i = 0; i < 4; ++i)
#pragma unroll
      for (int j = 0; j < 4; ++j)
        acc[i][j] = __builtin_amdgcn_mfma_f32_16x16x32_f16(af[i], bf[j], acc[i][j], 0, 0, 0);
  }
  const int t = (bm * 128 + wm) >> 6;  // wm in {0,64} -> t const per wave
#pragma unroll
  for (int j = 0; j < 4; ++j) {
    const int col = bn * 128 + wn + j * 16 + ml;
    const float bj = biasp[col];
    const int p = col >> 4;
#pragma unroll
    for (int i = 0; i < 4; ++i) {
      half4v pk = {(_Float16)(acc[i][j][0] + bj), (_Float16)(acc[i][j][1] + bj),
                   (_Float16)(acc[i][j][2] + bj), (_Float16)(acc[i][j][3] + bj)};
      *(half4v*)&G3[((size_t)p * 512 + t) * 1024 + i * 256 + kg * 64 + ml * 4] = pk;
    }
  }
}

// ---------------- persistent recurrent kernel ----------------
// 256 blocks (1/CU) x 4 waves. Block P = (bg = P>>6, ug = P&63): owns the output
// tile batches [16bg,16bg+16) x units [16ug,16ug+16) (perm cols [64ug,64ug+64)).
// Each block reads only its 16 batch rows of h = 32 KB/step (4x less LLC traffic
// and 4x less per-CU inflow than the 4-units-x-64-batches partition).
// 4 waves split K: wave kw loads h[16 rows][256 units] straight into REGISTERS
// (no LDS staging of A), runs 8 k-slices x 4 col-tiles of MFMA with persistent
// Wh fragments (128 VGPR), adds its G3 addend (old layout, p' = 4*ug+kw), and
// writes f32 partials to a 17 KB LDS buffer. One __syncthreads, then each thread
// (= one (batch,unit) pair) sums 4 float4s and does the gate math + publish.
// Grid barrier: R0's proven scheme (scattered flags + syncthreads_and + s_sleep).
__global__ __launch_bounds__(256, 1) void lstm_rec_kernel(
    const _Float16* __restrict__ G3, const _Float16* __restrict__ Whp,
    unsigned int* __restrict__ hbuf, const float* __restrict__ cx,
    float* __restrict__ out, unsigned int* __restrict__ flags) {
  const int P = blockIdx.x, tid = threadIdx.x;
  const int kw = tid >> 6, l = tid & 63;   // wave kw owns k-range [256kw, 256kw+256)
  const int ml = l & 15, kg = l >> 4;
  const int bg = P >> 6, ug = P & 63;
  __shared__ float pacc[4][16][68];        // [kw][batch16][col64], padded: 17408 B

  // persistent Wh B-fragments: wfr[cgt*8+s] = Whp[64ug+16cgt+ml][(8kw+s)*32 + kg*8 ..+8]
  half8 wfr[32];
#pragma unroll
  for (int cgt = 0; cgt < 4; ++cgt)
#pragma unroll
    for (int s = 0; s < 8; ++s)
      wfr[cgt * 8 + s] =
          *(const half8*)&Whp[(size_t)(64 * ug + 16 * cgt + ml) * 1024 + (8 * kw + s) * 32 + kg * 8];

  const int b16 = tid >> 4, u16 = tid & 15;  // consumer mapping: thread = (batch,unit)
  const int batch = 16 * bg + b16, U = 16 * ug + u16;
  float c = cx[batch * 1024 + U];
  __syncthreads();

  for (int t = 0; t < 512; ++t) {
    const u64* hq = (const u64*)(hbuf + (size_t)(t & 1) * 32768);
    u64* hnq = (u64*)(hbuf + (size_t)((t & 1) ^ 1) * 32768);

    // ---- issue all global traffic up front ----
    // lane (ml,kg) of wave kw: A-frag slice s needs h[16bg+ml][256kw+32s+8kg ..+8]
    // = u64 pair at hq[(16bg+ml)*256 + 64kw + 8s + 2kg]
    u64 cp[16];
#pragma unroll
    for (int s = 0; s < 8; ++s) {
      const size_t base = (size_t)(16 * bg + ml) * 256 + 64 * kw + 8 * s + 2 * kg;
      cp[2 * s] = __hip_atomic_load(&hq[base], __ATOMIC_RELAXED, __HIP_MEMORY_SCOPE_AGENT);
      cp[2 * s + 1] =
          __hip_atomic_load(&hq[base + 1], __ATOMIC_RELAXED, __HIP_MEMORY_SCOPE_AGENT);
    }
    // G3 addend for col-tile cgt==kw, old fragment layout with p' = 4*ug + kw
    const u64 ginb = *(const u64*)&G3[(((size_t)(4 * ug + kw) * 512 + t) * 1024) +
                                      bg * 256 + kg * 64 + ml * 4];

    // ---- MFMA: 8 k-slices x 4 col-tiles, A straight from registers ----
    floatx4 acc[4] = {};
#pragma unroll
    for (int s = 0; s < 8; ++s) {
      union { u64 q[2]; half8 h; } au;
      au.q[0] = cp[2 * s];
      au.q[1] = cp[2 * s + 1];
#pragma unroll
      for (int cgt = 0; cgt < 4; ++cgt)
        acc[cgt] = __builtin_amdgcn_mfma_f32_16x16x32_f16(au.h, wfr[cgt * 8 + s], acc[cgt], 0, 0, 0);
    }

    // ---- write partials (+G3 on own col-tile) to LDS ----
    union { u64 q; half4v h4; } gu; gu.q = ginb;
#pragma unroll
    for (int cgt = 0; cgt < 4; ++cgt) {
#pragma unroll
      for (int r = 0; r < 4; ++r) {
        float v = acc[cgt][r];
        if (cgt == kw) v += (float)gu.h4[r];
        pacc[kw][kg * 4 + r][16 * cgt + ml] = v;
      }
    }
    __syncthreads();

    // ---- consumer: sum 4 k-partials, gate math ----
    floatx4 ssum = *(const floatx4*)&pacc[0][b16][4 * u16];
#pragma unroll
    for (int kw2 = 1; kw2 < 4; ++kw2)
      ssum += *(const floatx4*)&pacc[kw2][b16][4 * u16];

    const float ig = sig_(ssum[0]), fg = sig_(ssum[1]);
    const float ag = tanh_(ssum[2]), og = sig_(ssum[3]);
    c = fg * c + ig * ag;
    const float h = og * tanh_(c);

    // publish: pack 4 units/batch -> one u64 agent store from lane u16%4==0
    unsigned int mine = (unsigned int)__builtin_bit_cast(unsigned short, (_Float16)h);
    unsigned int pair = mine | (((unsigned int)__shfl_xor((int)mine, 1)) << 16);
    u64 quad = (u64)pair | ((u64)(unsigned int)__shfl_xor((int)pair, 2) << 32);
    if ((u16 & 3) == 0)
      __hip_atomic_store(&hnq[(size_t)batch * 256 + 4 * ug + (u16 >> 2)], quad,
                         __ATOMIC_RELAXED, __HIP_MEMORY_SCOPE_AGENT);

    if (t == 511) {
      out[(size_t)t * 65536 + batch * 1024 + U] = h;
      out[(size_t)33554432 + batch * 1024 + U] = h;  // hy
      out[(size_t)33619968 + batch * 1024 + U] = c;  // cy
      break;
    }

    // ---- grid barrier (R0's proven scheme: scattered flags, throttled poll) ----
    __builtin_amdgcn_s_waitcnt(0x0F70);  // vmcnt(0): publish acked at coherence point
    __syncthreads();
    if (tid == 0)
      __hip_atomic_store(&flags[P * 32], (unsigned)(t + 1), __ATOMIC_RELAXED,
                         __HIP_MEMORY_SCOPE_AGENT);
    out[(size_t)t * 65536 + batch * 1024 + U] = h;  // off the critical path
    const unsigned tgt = (unsigned)(t + 1);
    int done;
    do {
      unsigned v = __hip_atomic_load(&flags[tid * 32], __ATOMIC_RELAXED,
                                     __HIP_MEMORY_SCOPE_AGENT);
      done = __syncthreads_and((int)(v >= tgt));
      if (!done) __builtin_amdgcn_s_sleep(2);
    } while (!done);
    asm volatile("" ::: "memory");
  }
}

// ---------------- launch ----------------
extern "C" void kernel_launch(void* const* d_in, const int* in_sizes, int n_in,
                              void* d_out, int out_size, void* d_ws, size_t ws_size,
                              hipStream_t stream) {
  const float* x    = (const float*)d_in[0];
  const float* hx   = (const float*)d_in[1];
  const float* cxp  = (const float*)d_in[2];
  const float* w_ii = (const float*)d_in[3];
  const float* w_fi = (const float*)d_in[4];
  const float* w_ai = (const float*)d_in[5];
  const float* w_oi = (const float*)d_in[6];
  const float* w_ih = (const float*)d_in[7];
  const float* w_fh = (const float*)d_in[8];
  const float* w_ah = (const float*)d_in[9];
  const float* w_oh = (const float*)d_in[10];
  const float* b_i  = (const float*)d_in[11];
  const float* b_f  = (const float*)d_in[12];
  const float* b_a  = (const float*)d_in[13];
  const float* b_o  = (const float*)d_in[14];
  float* out = (float*)d_out;

  char* ws = (char*)d_ws;
  _Float16* Xh        = (_Float16*)(ws);                 // 64 MB (dead after gemm_g)
  unsigned int* flags = (unsigned int*)(ws);             // 32 KB used, aliases Xh
  _Float16* Wip       = (_Float16*)(ws + 67108864);      // 8 MB
  _Float16* Whp       = (_Float16*)(ws + 75497472);      // 8 MB
  float* biasp        = (float*)(ws + 83886080);         // 16 KB
  unsigned int* hbuf  = (unsigned int*)(ws + 83902464);  // 256 KB (2 packed buffers)
  _Float16* G3        = (_Float16*)(ws + 84164864);      // 256 MB
  if (ws_size < (size_t)84164864 + 268435456) return;

  cvt_x_kernel<<<32768, 256, 0, stream>>>(x, Xh, 33554432);
  build_w_kernel<<<8193, 256, 0, stream>>>(w_ii, w_fi, w_ai, w_oi, w_ih, w_fh, w_ah, w_oh,
                                           b_i, b_f, b_a, b_o, Wip, Whp, biasp);
  init_h_kernel<<<128, 256, 0, stream>>>(hx, hbuf);
  gemm_g_kernel<<<dim3(256, 32), 256, 0, stream>>>(Xh, Wip, biasp, G3);
  zero_flags_kernel<<<32, 256, 0, stream>>>(flags);
  lstm_rec_kernel<<<256, 256, 0, stream>>>(G3, Whp, hbuf, cxp, out, flags);
}

// Round 4
// 3158.114 us; speedup vs baseline: 1.6910x; 1.0934x over previous
//
#include <hip/hip_runtime.h>
#include <cstdint>

typedef _Float16 half8 __attribute__((ext_vector_type(8)));
typedef _Float16 half4v __attribute__((ext_vector_type(4)));
typedef float floatx4 __attribute__((ext_vector_type(4)));
typedef unsigned long long u64;

__device__ __forceinline__ float sig_(float x) { return 1.f / (1.f + __expf(-x)); }
__device__ __forceinline__ float tanh_(float x) {
  x = fminf(15.f, fmaxf(-15.f, x));
  float e = __expf(2.f * x);
  return (e - 1.f) / (e + 1.f);
}

// ---------------- prep kernels ----------------
__global__ void cvt_x_kernel(const float* __restrict__ x, _Float16* __restrict__ xh, int n) {
  int i = (blockIdx.x * 256 + threadIdx.x) * 4;
  if (i < n) {
    const float4 v = *(const float4*)(x + i);
    half4v o = {(_Float16)v.x, (_Float16)v.y, (_Float16)v.z, (_Float16)v.w};
    *(half4v*)(xh + i) = o;
  }
}

// Permuted weights: row n of W*perm = w_{g}[u][:], u=n>>2, g=n&3.
__global__ void build_w_kernel(const float* w0, const float* w1, const float* w2, const float* w3,
                               const float* w4, const float* w5, const float* w6, const float* w7,
                               const float* b0, const float* b1, const float* b2, const float* b3,
                               _Float16* __restrict__ Wip, _Float16* __restrict__ Whp,
                               float* __restrict__ biasp) {
  int n = blockIdx.x;
  if (n < 8192) {
    const float* srcs[8] = {w0, w1, w2, w3, w4, w5, w6, w7};
    int which = n >> 12;
    int row = n & 4095;
    int u = row >> 2, g = row & 3;
    const float* s = srcs[which * 4 + g] + (size_t)u * 1024;
    _Float16* dst = (which ? Whp : Wip) + (size_t)row * 1024;
    int t = threadIdx.x * 4;
    float4 v = *(const float4*)(s + t);
    half4v o = {(_Float16)v.x, (_Float16)v.y, (_Float16)v.z, (_Float16)v.w};
    *(half4v*)(dst + t) = o;
  } else {
    const float* bs[4] = {b0, b1, b2, b3};
    for (int idx = threadIdx.x; idx < 4096; idx += 256)
      biasp[idx] = bs[idx & 3][idx >> 2];
  }
}

// h buffers: fp16 pairs packed in u32, row-major [batch][unit]
__global__ void init_h_kernel(const float* __restrict__ hx, unsigned int* __restrict__ hbuf) {
  int i = blockIdx.x * 256 + threadIdx.x;
  if (i < 32768) {
    unsigned short lo = __builtin_bit_cast(unsigned short, (_Float16)hx[2 * i]);
    unsigned short hi = __builtin_bit_cast(unsigned short, (_Float16)hx[2 * i + 1]);
    hbuf[i] = (unsigned int)lo | ((unsigned int)hi << 16);
  }
}

__global__ void zero_flags_kernel(unsigned int* __restrict__ flags) {
  int i = blockIdx.x * 256 + threadIdx.x;
  if (i < 8192) flags[i] = 0u;
}

// ---------------- precompute GEMM ----------------
// G3 layout (fp16): [p(256)][t(512)][i(4)][kg(4)][ml(16)][r(4)] — unchanged.
__global__ __launch_bounds__(256) void gemm_g_kernel(const _Float16* __restrict__ Xh,
                                                     const _Float16* __restrict__ Wp,
                                                     const float* __restrict__ biasp,
                                                     _Float16* __restrict__ G3) {
  __shared__ _Float16 Al[4][128][8];
  __shared__ _Float16 Bl[4][128][8];
  const int tid = threadIdx.x;
  const int w = tid >> 6, l = tid & 63;
  const int wm = (w >> 1) * 64, wn = (w & 1) * 64;
  const int ml = l & 15, kg = l >> 4;
  const int bm = blockIdx.x, bn = blockIdx.y;
  const int r0 = tid & 127, kc0 = tid >> 7;
  const int kc1 = kc0 + 2;
  const size_t arow0 = (size_t)(bm * 128 + r0) * 1024;
  const size_t brow0 = (size_t)(bn * 128 + r0) * 1024;
  floatx4 acc[4][4] = {};
  for (int kt = 0; kt < 1024; kt += 32) {
    __syncthreads();
    __builtin_amdgcn_global_load_lds(
        (const __attribute__((address_space(1))) unsigned int*)(Xh + arow0 + kt + kc0 * 8),
        (__attribute__((address_space(3))) unsigned int*)&Al[kc0][r0][0], 16, 0, 0);
    __builtin_amdgcn_global_load_lds(
        (const __attribute__((address_space(1))) unsigned int*)(Xh + arow0 + kt + kc1 * 8),
        (__attribute__((address_space(3))) unsigned int*)&Al[kc1][r0][0], 16, 0, 0);
    __builtin_amdgcn_global_load_lds(
        (const __attribute__((address_space(1))) unsigned int*)(Wp + brow0 + kt + kc0 * 8),
        (__attribute__((address_space(3))) unsigned int*)&Bl[kc0][r0][0], 16, 0, 0);
    __builtin_amdgcn_global_load_lds(
        (const __attribute__((address_space(1))) unsigned int*)(Wp + brow0 + kt + kc1 * 8),
        (__attribute__((address_space(3))) unsigned int*)&Bl[kc1][r0][0], 16, 0, 0);
    __syncthreads();
    half8 af[4], bf[4];
#pragma unroll
    for (int i = 0; i < 4; ++i) af[i] = *(const half8*)&Al[kg][wm + i * 16 + ml][0];
#pragma unroll
    for (int j = 0; j < 4; ++j) bf[j] = *(const half8*)&Bl[kg][wn + j * 16 + ml][0];
#pragma unroll
    for (int i = 0; i < 4; ++i)
#pragma unroll
      for (int j = 0; j < 4; ++j)
        acc[i][j] = __builtin_amdgcn_mfma_f32_16x16x32_f16(af[i], bf[j], acc[i][j], 0, 0, 0);
  }
  const int t = (bm * 128 + wm) >> 6;  // wm in {0,64} -> t const per wave
#pragma unroll
  for (int j = 0; j < 4; ++j) {
    const int col = bn * 128 + wn + j * 16 + ml;
    const float bj = biasp[col];
    const int p = col >> 4;
#pragma unroll
    for (int i = 0; i < 4; ++i) {
      half4v pk = {(_Float16)(acc[i][j][0] + bj), (_Float16)(acc[i][j][1] + bj),
                   (_Float16)(acc[i][j][2] + bj), (_Float16)(acc[i][j][3] + bj)};
      *(half4v*)&G3[((size_t)p * 512 + t) * 1024 + i * 256 + kg * 64 + ml * 4] = pk;
    }
  }
}

// ---------------- persistent recurrent kernel ----------------
// 256 blocks (1/CU) x 4 waves. Block P = (bg = P>>6, ug = P&63): owns the output
// tile batches [16bg,16bg+16) x units [16ug,16ug+16) (perm cols [64ug,64ug+64)).
// Dependency graph decomposes by bg: block (bg,ug) reads h rows [16bg,+16), which
// are written ONLY by blocks (bg,*). So the grid barrier is split into 4
// independent 64-block barriers (threads 0..63 poll same-bg flags; others vote
// true) — smaller wait set, less straggler jitter, groups fully decoupled.
// G3 addend for step t+1 is prefetched before the poll (HBM ~900cy hidden under
// the barrier wait instead of sitting on the post-release critical path).
__global__ __launch_bounds__(256, 1) void lstm_rec_kernel(
    const _Float16* __restrict__ G3, const _Float16* __restrict__ Whp,
    unsigned int* __restrict__ hbuf, const float* __restrict__ cx,
    float* __restrict__ out, unsigned int* __restrict__ flags) {
  const int P = blockIdx.x, tid = threadIdx.x;
  const int kw = tid >> 6, l = tid & 63;   // wave kw owns k-range [256kw, 256kw+256)
  const int ml = l & 15, kg = l >> 4;
  const int bg = P >> 6, ug = P & 63;
  __shared__ float pacc[4][16][68];        // [kw][batch16][col64], padded: 17408 B

  // persistent Wh B-fragments: wfr[cgt*8+s] = Whp[64ug+16cgt+ml][(8kw+s)*32 + kg*8 ..+8]
  half8 wfr[32];
#pragma unroll
  for (int cgt = 0; cgt < 4; ++cgt)
#pragma unroll
    for (int s = 0; s < 8; ++s)
      wfr[cgt * 8 + s] =
          *(const half8*)&Whp[(size_t)(64 * ug + 16 * cgt + ml) * 1024 + (8 * kw + s) * 32 + kg * 8];

  const int b16 = tid >> 4, u16 = tid & 15;  // consumer mapping: thread = (batch,unit)
  const int batch = 16 * bg + b16, U = 16 * ug + u16;
  float c = cx[batch * 1024 + U];
  const size_t gbase = ((size_t)(4 * ug + kw) * 512) * 1024 + bg * 256 + kg * 64 + ml * 4;
  u64 ginb = *(const u64*)&G3[gbase];  // addend for t=0
  __syncthreads();

  for (int t = 0; t < 512; ++t) {
    const u64* hq = (const u64*)(hbuf + (size_t)(t & 1) * 32768);
    u64* hnq = (u64*)(hbuf + (size_t)((t & 1) ^ 1) * 32768);

    // ---- issue all global traffic up front ----
    // lane (ml,kg) of wave kw: A-frag slice s needs h[16bg+ml][256kw+32s+8kg ..+8]
    // = u64 pair at hq[(16bg+ml)*256 + 64kw + 8s + 2kg]
    u64 cp[16];
#pragma unroll
    for (int s = 0; s < 8; ++s) {
      const size_t base = (size_t)(16 * bg + ml) * 256 + 64 * kw + 8 * s + 2 * kg;
      cp[2 * s] = __hip_atomic_load(&hq[base], __ATOMIC_RELAXED, __HIP_MEMORY_SCOPE_AGENT);
      cp[2 * s + 1] =
          __hip_atomic_load(&hq[base + 1], __ATOMIC_RELAXED, __HIP_MEMORY_SCOPE_AGENT);
    }

    // ---- MFMA: 8 k-slices x 4 col-tiles, A straight from registers ----
    floatx4 acc[4] = {};
#pragma unroll
    for (int s = 0; s < 8; ++s) {
      union { u64 q[2]; half8 h; } au;
      au.q[0] = cp[2 * s];
      au.q[1] = cp[2 * s + 1];
#pragma unroll
      for (int cgt = 0; cgt < 4; ++cgt)
        acc[cgt] = __builtin_amdgcn_mfma_f32_16x16x32_f16(au.h, wfr[cgt * 8 + s], acc[cgt], 0, 0, 0);
    }

    // ---- write partials (+G3 on own col-tile) to LDS ----
    union { u64 q; half4v h4; } gu; gu.q = ginb;
#pragma unroll
    for (int cgt = 0; cgt < 4; ++cgt) {
#pragma unroll
      for (int r = 0; r < 4; ++r) {
        float v = acc[cgt][r];
        if (cgt == kw) v += (float)gu.h4[r];
        pacc[kw][kg * 4 + r][16 * cgt + ml] = v;
      }
    }
    __syncthreads();

    // ---- consumer: sum 4 k-partials, gate math ----
    floatx4 ssum = *(const floatx4*)&pacc[0][b16][4 * u16];
#pragma unroll
    for (int kw2 = 1; kw2 < 4; ++kw2)
      ssum += *(const floatx4*)&pacc[kw2][b16][4 * u16];

    const float ig = sig_(ssum[0]), fg = sig_(ssum[1]);
    const float ag = tanh_(ssum[2]), og = sig_(ssum[3]);
    c = fg * c + ig * ag;
    const float h = og * tanh_(c);

    // publish: pack 4 units/batch -> one u64 agent store from lane u16%4==0
    unsigned int mine = (unsigned int)__builtin_bit_cast(unsigned short, (_Float16)h);
    unsigned int pair = mine | (((unsigned int)__shfl_xor((int)mine, 1)) << 16);
    u64 quad = (u64)pair | ((u64)(unsigned int)__shfl_xor((int)pair, 2) << 32);
    if ((u16 & 3) == 0)
      __hip_atomic_store(&hnq[(size_t)batch * 256 + 4 * ug + (u16 >> 2)], quad,
                         __ATOMIC_RELAXED, __HIP_MEMORY_SCOPE_AGENT);

    if (t == 511) {
      out[(size_t)t * 65536 + batch * 1024 + U] = h;
      out[(size_t)33554432 + batch * 1024 + U] = h;  // hy
      out[(size_t)33619968 + batch * 1024 + U] = c;  // cy
      break;
    }

    // ---- group barrier over 64 same-bg blocks (scattered flags, throttled) ----
    __builtin_amdgcn_s_waitcnt(0x0F70);  // vmcnt(0): publish acked at coherence point
    __syncthreads();
    if (tid == 0)
      __hip_atomic_store(&flags[P * 32], (unsigned)(t + 1), __ATOMIC_RELAXED,
                         __HIP_MEMORY_SCOPE_AGENT);
    out[(size_t)t * 65536 + batch * 1024 + U] = h;      // off the critical path
    const u64 gnext = *(const u64*)&G3[gbase + (size_t)(t + 1) * 1024];  // prefetch under poll
    const unsigned tgt = (unsigned)(t + 1);
    int done;
    do {
      unsigned v = tgt;
      if (tid < 64)
        v = __hip_atomic_load(&flags[(bg * 64 + tid) * 32], __ATOMIC_RELAXED,
                              __HIP_MEMORY_SCOPE_AGENT);
      done = __syncthreads_and((int)(v >= tgt));
      if (!done) __builtin_amdgcn_s_sleep(2);
    } while (!done);
    asm volatile("" ::: "memory");
    ginb = gnext;
  }
}

// ---------------- launch ----------------
extern "C" void kernel_launch(void* const* d_in, const int* in_sizes, int n_in,
                              void* d_out, int out_size, void* d_ws, size_t ws_size,
                              hipStream_t stream) {
  const float* x    = (const float*)d_in[0];
  const float* hx   = (const float*)d_in[1];
  const float* cxp  = (const float*)d_in[2];
  const float* w_ii = (const float*)d_in[3];
  const float* w_fi = (const float*)d_in[4];
  const float* w_ai = (const float*)d_in[5];
  const float* w_oi = (const float*)d_in[6];
  const float* w_ih = (const float*)d_in[7];
  const float* w_fh = (const float*)d_in[8];
  const float* w_ah = (const float*)d_in[9];
  const float* w_oh = (const float*)d_in[10];
  const float* b_i  = (const float*)d_in[11];
  const float* b_f  = (const float*)d_in[12];
  const float* b_a  = (const float*)d_in[13];
  const float* b_o  = (const float*)d_in[14];
  float* out = (float*)d_out;

  char* ws = (char*)d_ws;
  _Float16* Xh        = (_Float16*)(ws);                 // 64 MB (dead after gemm_g)
  unsigned int* flags = (unsigned int*)(ws);             // 32 KB used, aliases Xh
  _Float16* Wip       = (_Float16*)(ws + 67108864);      // 8 MB
  _Float16* Whp       = (_Float16*)(ws + 75497472);      // 8 MB
  float* biasp        = (float*)(ws + 83886080);         // 16 KB
  unsigned int* hbuf  = (unsigned int*)(ws + 83902464);  // 256 KB (2 packed buffers)
  _Float16* G3        = (_Float16*)(ws + 84164864);      // 256 MB
  if (ws_size < (size_t)84164864 + 268435456) return;

  cvt_x_kernel<<<32768, 256, 0, stream>>>(x, Xh, 33554432);
  build_w_kernel<<<8193, 256, 0, stream>>>(w_ii, w_fi, w_ai, w_oi, w_ih, w_fh, w_ah, w_oh,
                                           b_i, b_f, b_a, b_o, Wip, Whp, biasp);
  init_h_kernel<<<128, 256, 0, stream>>>(hx, hbuf);
  gemm_g_kernel<<<dim3(256, 32), 256, 0, stream>>>(Xh, Wip, biasp, G3);
  zero_flags_kernel<<<32, 256, 0, stream>>>(flags);
  lstm_rec_kernel<<<256, 256, 0, stream>>>(G3, Whp, hbuf, cxp, out, flags);
}

// Round 6
// 3092.861 us; speedup vs baseline: 1.7267x; 1.0211x over previous
//
#include <hip/hip_runtime.h>
#include <cstdint>

typedef _Float16 half8 __attribute__((ext_vector_type(8)));
typedef _Float16 half4v __attribute__((ext_vector_type(4)));
typedef float floatx4 __attribute__((ext_vector_type(4)));
typedef unsigned long long u64;

__device__ __forceinline__ float sig_(float x) { return 1.f / (1.f + __expf(-x)); }
__device__ __forceinline__ float tanh_(float x) {
  x = fminf(15.f, fmaxf(-15.f, x));
  float e = __expf(2.f * x);
  return (e - 1.f) / (e + 1.f);
}

// ---------------- prep kernels ----------------
__global__ void cvt_x_kernel(const float* __restrict__ x, _Float16* __restrict__ xh, int n) {
  int i = (blockIdx.x * 256 + threadIdx.x) * 4;
  if (i < n) {
    const float4 v = *(const float4*)(x + i);
    half4v o = {(_Float16)v.x, (_Float16)v.y, (_Float16)v.z, (_Float16)v.w};
    *(half4v*)(xh + i) = o;
  }
}

// Permuted weights: row n of W*perm = w_{g}[u][:], u=n>>2, g=n&3.
__global__ void build_w_kernel(const float* w0, const float* w1, const float* w2, const float* w3,
                               const float* w4, const float* w5, const float* w6, const float* w7,
                               const float* b0, const float* b1, const float* b2, const float* b3,
                               _Float16* __restrict__ Wip, _Float16* __restrict__ Whp,
                               float* __restrict__ biasp) {
  int n = blockIdx.x;
  if (n < 8192) {
    const float* srcs[8] = {w0, w1, w2, w3, w4, w5, w6, w7};
    int which = n >> 12;
    int row = n & 4095;
    int u = row >> 2, g = row & 3;
    const float* s = srcs[which * 4 + g] + (size_t)u * 1024;
    _Float16* dst = (which ? Whp : Wip) + (size_t)row * 1024;
    int t = threadIdx.x * 4;
    float4 v = *(const float4*)(s + t);
    half4v o = {(_Float16)v.x, (_Float16)v.y, (_Float16)v.z, (_Float16)v.w};
    *(half4v*)(dst + t) = o;
  } else {
    const float* bs[4] = {b0, b1, b2, b3};
    for (int idx = threadIdx.x; idx < 4096; idx += 256)
      biasp[idx] = bs[idx & 3][idx >> 2];
  }
}

// slot 0 of the h history: fp16 pairs packed in u32, row-major [batch][unit]
__global__ void init_h_kernel(const float* __restrict__ hx, unsigned int* __restrict__ h0) {
  int i = blockIdx.x * 256 + threadIdx.x;
  if (i < 32768) {
    unsigned short lo = __builtin_bit_cast(unsigned short, (_Float16)hx[2 * i]);
    unsigned short hi = __builtin_bit_cast(unsigned short, (_Float16)hx[2 * i + 1]);
    h0[i] = (unsigned int)lo | ((unsigned int)hi << 16);
  }
}

// fill h-history slots 1..511 with the NaN sentinel (slot stride 16384 u64)
__global__ void sent_fill_kernel(u64* __restrict__ Hq) {
  size_t i = ((size_t)blockIdx.x * 256 + threadIdx.x) * 4 + 16384;
  const u64 s = 0x7FFF7FFF7FFF7FFFull;
  if (i < 8388608) { Hq[i] = s; Hq[i + 1] = s; Hq[i + 2] = s; Hq[i + 3] = s; }
}

// ---------------- precompute GEMM ----------------
// G3 layout (fp16): [p(256)][t(512)][i(4)][kg(4)][ml(16)][r(4)] — unchanged.
__global__ __launch_bounds__(256) void gemm_g_kernel(const _Float16* __restrict__ Xh,
                                                     const _Float16* __restrict__ Wp,
                                                     const float* __restrict__ biasp,
                                                     _Float16* __restrict__ G3) {
  __shared__ _Float16 Al[4][128][8];
  __shared__ _Float16 Bl[4][128][8];
  const int tid = threadIdx.x;
  const int w = tid >> 6, l = tid & 63;
  const int wm = (w >> 1) * 64, wn = (w & 1) * 64;
  const int ml = l & 15, kg = l >> 4;
  const int bm = blockIdx.x, bn = blockIdx.y;
  const int r0 = tid & 127, kc0 = tid >> 7;
  const int kc1 = kc0 + 2;
  const size_t arow0 = (size_t)(bm * 128 + r0) * 1024;
  const size_t brow0 = (size_t)(bn * 128 + r0) * 1024;
  floatx4 acc[4][4] = {};
  for (int kt = 0; kt < 1024; kt += 32) {
    __syncthreads();
    __builtin_amdgcn_global_load_lds(
        (const __attribute__((address_space(1))) unsigned int*)(Xh + arow0 + kt + kc0 * 8),
        (__attribute__((address_space(3))) unsigned int*)&Al[kc0][r0][0], 16, 0, 0);
    __builtin_amdgcn_global_load_lds(
        (const __attribute__((address_space(1))) unsigned int*)(Xh + arow0 + kt + kc1 * 8),
        (__attribute__((address_space(3))) unsigned int*)&Al[kc1][r0][0], 16, 0, 0);
    __builtin_amdgcn_global_load_lds(
        (const __attribute__((address_space(1))) unsigned int*)(Wp + brow0 + kt + kc0 * 8),
        (__attribute__((address_space(3))) unsigned int*)&Bl[kc0][r0][0], 16, 0, 0);
    __builtin_amdgcn_global_load_lds(
        (const __attribute__((address_space(1))) unsigned int*)(Wp + brow0 + kt + kc1 * 8),
        (__attribute__((address_space(3))) unsigned int*)&Bl[kc1][r0][0], 16, 0, 0);
    __syncthreads();
    half8 af[4], bf[4];
#pragma unroll
    for (int i = 0; i < 4; ++i) af[i] = *(const half8*)&Al[kg][wm + i * 16 + ml][0];
#pragma unroll
    for (int j = 0; j < 4; ++j) bf[j] = *(const half8*)&Bl[kg][wn + j * 16 + ml][0];
#pragma unroll
    for (int i = 0; i < 4; ++i)
#pragma unroll
      for (int j = 0; j < 4; ++j)
        acc[i][j] = __builtin_amdgcn_mfma_f32_16x16x32_f16(af[i], bf[j], acc[i][j], 0, 0, 0);
  }
  const int t = (bm * 128 + wm) >> 6;  // wm in {0,64} -> t const per wave
#pragma unroll
  for (int j = 0; j < 4; ++j) {
    const int col = bn * 128 + wn + j * 16 + ml;
    const float bj = biasp[col];
    const int p = col >> 4;
#pragma unroll
    for (int i = 0; i < 4; ++i) {
      half4v pk = {(_Float16)(acc[i][j][0] + bj), (_Float16)(acc[i][j][1] + bj),
                   (_Float16)(acc[i][j][2] + bj), (_Float16)(acc[i][j][3] + bj)};
      *(half4v*)&G3[((size_t)p * 512 + t) * 1024 + i * 256 + kg * 64 + ml * 4] = pk;
    }
  }
}

// ---------------- persistent recurrent kernel (dataflow, no barrier) ----------------
// 256 blocks (1/CU) x 4 waves. Block P = (bg = P>>6, ug = P&63): owns batches
// [16bg,+16) x units [16ug,+16). h lives in a PER-STEP history buffer Hq
// (512 slots x 128 KB, slot t = h(t); slot 0 = hx). Slots 1..511 pre-filled with
// the fp16-NaN sentinel. Consumers POLL THE DATA ITSELF; a slot u64 is accepted
// only when BOTH dword halves != 0x7FFF7FFF (a data dword can never be two fp16
// NaNs since h = sig*tanh is finite) — so the check is correct even if the 8B
// publish store tears into two dword writes. Retry path is s_sleep-throttled
// (matches every poll that has worked on this chip; avoids LLC livelock).
// One coherence hop instead of three; no grid/group barrier at all.
__global__ __launch_bounds__(256, 1) void lstm_rec_kernel(
    const _Float16* __restrict__ G3, const _Float16* __restrict__ Whp,
    u64* __restrict__ Hq, const float* __restrict__ cx,
    float* __restrict__ out) {
  const int P = blockIdx.x, tid = threadIdx.x;
  const int kw = tid >> 6, l = tid & 63;   // wave kw owns k-range [256kw, 256kw+256)
  const int ml = l & 15, kg = l >> 4;
  const int bg = P >> 6, ug = P & 63;
  const unsigned SENT32 = 0x7FFF7FFFu;
  __shared__ float pacc[4][16][68];        // [kw][batch16][col64], padded: 17408 B

  // persistent Wh B-fragments: wfr[cgt*8+s] = Whp[64ug+16cgt+ml][(8kw+s)*32 + kg*8 ..+8]
  half8 wfr[32];
#pragma unroll
  for (int cgt = 0; cgt < 4; ++cgt)
#pragma unroll
    for (int s = 0; s < 8; ++s)
      wfr[cgt * 8 + s] =
          *(const half8*)&Whp[(size_t)(64 * ug + 16 * cgt + ml) * 1024 + (8 * kw + s) * 32 + kg * 8];

  const int b16 = tid >> 4, u16 = tid & 15;  // consumer mapping: thread = (batch,unit)
  const int batch = 16 * bg + b16, U = 16 * ug + u16;
  float c = cx[batch * 1024 + U];
  const size_t gbase = ((size_t)(4 * ug + kw) * 512) * 1024 + bg * 256 + kg * 64 + ml * 4;
  u64 ginb = *(const u64*)&G3[gbase];  // addend for t=0
  // lane (ml,kg) of wave kw: load i (i=2s+j) = h(t)[16bg+ml][...] at
  // slot_base + (16bg+ml)*256 + 64kw + 8s + 2kg + j
  const size_t lbase = (size_t)(16 * bg + ml) * 256 + 64 * kw + 2 * kg;
  __syncthreads();

  for (int t = 0; t < 512; ++t) {
    const u64* hs = Hq + (size_t)t * 16384;

    // ---- poll the data: load 16 u64s, retry only not-yet-ready entries ----
    u64 cp[16];
#pragma unroll
    for (int i = 0; i < 16; ++i)
      cp[i] = __hip_atomic_load(&hs[lbase + 8 * (i >> 1) + (i & 1)], __ATOMIC_RELAXED,
                                __HIP_MEMORY_SCOPE_AGENT);
    for (;;) {
      int myok = 1;
#pragma unroll
      for (int i = 0; i < 16; ++i)
        myok &= ((unsigned)cp[i] != SENT32) & ((unsigned)(cp[i] >> 32) != SENT32);
      if (__all(myok)) break;
      __builtin_amdgcn_s_sleep(1);  // throttle: only reached while waiting
#pragma unroll
      for (int i = 0; i < 16; ++i)
        if (((unsigned)cp[i] == SENT32) | ((unsigned)(cp[i] >> 32) == SENT32))
          cp[i] = __hip_atomic_load(&hs[lbase + 8 * (i >> 1) + (i & 1)], __ATOMIC_RELAXED,
                                    __HIP_MEMORY_SCOPE_AGENT);
    }

    // ---- MFMA: 8 k-slices x 4 col-tiles, A straight from registers ----
    floatx4 acc[4] = {};
#pragma unroll
    for (int s = 0; s < 8; ++s) {
      union { u64 q[2]; half8 h; } au;
      au.q[0] = cp[2 * s];
      au.q[1] = cp[2 * s + 1];
#pragma unroll
      for (int cgt = 0; cgt < 4; ++cgt)
        acc[cgt] = __builtin_amdgcn_mfma_f32_16x16x32_f16(au.h, wfr[cgt * 8 + s], acc[cgt], 0, 0, 0);
    }

    // ---- write partials (+G3 on own col-tile) to LDS ----
    union { u64 q; half4v h4; } gu; gu.q = ginb;
#pragma unroll
    for (int cgt = 0; cgt < 4; ++cgt) {
#pragma unroll
      for (int r = 0; r < 4; ++r) {
        float v = acc[cgt][r];
        if (cgt == kw) v += (float)gu.h4[r];
        pacc[kw][kg * 4 + r][16 * cgt + ml] = v;
      }
    }
    __syncthreads();

    // ---- consumer: sum 4 k-partials, gate math ----
    floatx4 ssum = *(const floatx4*)&pacc[0][b16][4 * u16];
#pragma unroll
    for (int kw2 = 1; kw2 < 4; ++kw2)
      ssum += *(const floatx4*)&pacc[kw2][b16][4 * u16];
    __syncthreads();  // pacc reads done before any wave's next-step writes

    const float ig = sig_(ssum[0]), fg = sig_(ssum[1]);
    const float ag = tanh_(ssum[2]), og = sig_(ssum[3]);
    c = fg * c + ig * ag;
    const float h = og * tanh_(c);

    // pack 4 units/batch -> one u64 from lane u16%4==0
    unsigned int mine = (unsigned int)__builtin_bit_cast(unsigned short, (_Float16)h);
    unsigned int pair = mine | (((unsigned int)__shfl_xor((int)mine, 1)) << 16);
    u64 quad = (u64)pair | ((u64)(unsigned int)__shfl_xor((int)pair, 2) << 32);

    if (t == 511) {
      out[(size_t)t * 65536 + batch * 1024 + U] = h;
      out[(size_t)33554432 + batch * 1024 + U] = h;  // hy
      out[(size_t)33619968 + batch * 1024 + U] = c;  // cy
      break;
    }

    // publish h(t+1): the store IS the ready signal
    if ((u16 & 3) == 0)
      __hip_atomic_store(&Hq[(size_t)(t + 1) * 16384 + (size_t)batch * 256 + 4 * ug + (u16 >> 2)],
                         quad, __ATOMIC_RELAXED, __HIP_MEMORY_SCOPE_AGENT);

    out[(size_t)t * 65536 + batch * 1024 + U] = h;   // off the critical path
    ginb = *(const u64*)&G3[gbase + (size_t)(t + 1) * 1024];  // prefetch under next poll
    asm volatile("" ::: "memory");
  }
}

// ---------------- launch ----------------
extern "C" void kernel_launch(void* const* d_in, const int* in_sizes, int n_in,
                              void* d_out, int out_size, void* d_ws, size_t ws_size,
                              hipStream_t stream) {
  const float* x    = (const float*)d_in[0];
  const float* hx   = (const float*)d_in[1];
  const float* cxp  = (const float*)d_in[2];
  const float* w_ii = (const float*)d_in[3];
  const float* w_fi = (const float*)d_in[4];
  const float* w_ai = (const float*)d_in[5];
  const float* w_oi = (const float*)d_in[6];
  const float* w_ih = (const float*)d_in[7];
  const float* w_fh = (const float*)d_in[8];
  const float* w_ah = (const float*)d_in[9];
  const float* w_oh = (const float*)d_in[10];
  const float* b_i  = (const float*)d_in[11];
  const float* b_f  = (const float*)d_in[12];
  const float* b_a  = (const float*)d_in[13];
  const float* b_o  = (const float*)d_in[14];
  float* out = (float*)d_out;

  char* ws = (char*)d_ws;
  _Float16* Xh        = (_Float16*)(ws);                 // 64 MB (dead after gemm_g)
  u64* Hq             = (u64*)(ws);                      // 64 MB h history, aliases Xh
  _Float16* Wip       = (_Float16*)(ws + 67108864);      // 8 MB
  _Float16* Whp       = (_Float16*)(ws + 75497472);      // 8 MB
  float* biasp        = (float*)(ws + 83886080);         // 16 KB
  _Float16* G3        = (_Float16*)(ws + 84164864);      // 256 MB
  if (ws_size < (size_t)84164864 + 268435456) return;

  cvt_x_kernel<<<32768, 256, 0, stream>>>(x, Xh, 33554432);
  build_w_kernel<<<8193, 256, 0, stream>>>(w_ii, w_fi, w_ai, w_oi, w_ih, w_fh, w_ah, w_oh,
                                           b_i, b_f, b_a, b_o, Wip, Whp, biasp);
  gemm_g_kernel<<<dim3(256, 32), 256, 0, stream>>>(Xh, Wip, biasp, G3);
  // Xh dead from here; its region becomes the h history
  sent_fill_kernel<<<8176, 256, 0, stream>>>(Hq);
  init_h_kernel<<<128, 256, 0, stream>>>(hx, (unsigned int*)Hq);
  lstm_rec_kernel<<<256, 256, 0, stream>>>(G3, Whp, Hq, cxp, out);
}